// Round 1
// baseline (76.035 us; speedup 1.0000x reference)
//
#include <hip/hip_runtime.h>
#include <math.h>
#include <float.h>

#define NMAX 512
#define TILE 16

// ---------------- Kernel 1: per-Gaussian prep + depth sort ----------------
// One block of 512 threads. Computes projection, 2D covariance, conic,
// tile bbox, opacity/color; bitonic-sorts by depth (tie-break index = stable
// argsort equivalent); writes SoA sorted arrays to ws.
//
// ws layout (floats, stride NMAX):
//  [0]=mx [1]=my [2]=i00 [3]=i01 [4]=i10 [5]=i11 [6]=O [7]=C0 [8]=C1 [9]=C2
//  [10]=packed tile bounds (int: xmin | xmax<<8 | ymin<<16 | ymax<<24)
__global__ __launch_bounds__(NMAX) void prep_kernel(
    const float* __restrict__ mu, const float* __restrict__ scales,
    const float* __restrict__ quats, const float* __restrict__ cols,
    const float* __restrict__ opcs, const float* __restrict__ vm,
    const int* __restrict__ focal_p, const int* __restrict__ H_p,
    const int* __restrict__ W_p, float* __restrict__ ws, int N)
{
    __shared__ float skey[NMAX];
    __shared__ int   sidx[NMAX];
    __shared__ float s_mx[NMAX], s_my[NMAX];
    __shared__ float s_i00[NMAX], s_i01[NMAX], s_i10[NMAX], s_i11[NMAX];
    __shared__ float s_O[NMAX], s_c0[NMAX], s_c1[NMAX], s_c2[NMAX];
    __shared__ int   s_bnd[NMAX];

    const int g = threadIdx.x;
    float key = FLT_MAX;

    if (g < N) {
        const int   Wi = W_p[0], Hi = H_p[0];
        const float fx = (float)focal_p[0];
        const float fy = fx;
        const float Wf = (float)Wi, Hf = (float)Hi;
        const float cxf = (float)((double)Wi / 2.0);
        const float cyf = (float)((double)Hi / 2.0);

        const float m0 = mu[3*g], m1 = mu[3*g+1], m2 = mu[3*g+2];
        const float t0 = vm[0]*m0  + vm[1]*m1  + vm[2]*m2  + vm[3];
        const float t1 = vm[4]*m0  + vm[5]*m1  + vm[6]*m2  + vm[7];
        const float t2 = vm[8]*m0  + vm[9]*m1  + vm[10]*m2 + vm[11];
        const float t3 = vm[12]*m0 + vm[13]*m1 + vm[14]*m2 + vm[15];

        // depth = (f+n)/(f-n)*t2 + (-2fn/(f-n))*t3   (n=0.01, f=10)
        const float dc1 = (float)((10.0 + 0.01) / (10.0 - 0.01));
        const float dc2 = (float)(-2.0 * 10.0 * 0.01 / (10.0 - 0.01));
        key = dc1 * t2 + dc2 * t3;

        // screen xy
        const float sxc = (float)(2.0 * (double)fx / (double)Wi);
        const float syc = (float)(2.0 * (double)fy / (double)Hi);
        const float tp0 = sxc * t0;
        const float tp1 = syc * t1;
        const float mx = Wf * tp0 / t2 / 2.0f + cxf;
        const float my = Hf * tp1 / t2 / 2.0f + cyf;

        // quaternion -> R  (replicating the reference's exact formulas,
        // including its non-standard r11 and r20 entries)
        const float qx = quats[4*g], qy = quats[4*g+1], qz = quats[4*g+2], qw = quats[4*g+3];
        const float R00 = 1.0f - 2.0f*(qy*qy + qz*qz);
        const float R01 = 2.0f*(qx*qy - qw*qz);
        const float R02 = 2.0f*(qx*qz + qw*qy);
        const float R10 = 2.0f*(qx*qy + qw*qz);
        const float R11 = 1.0f - 2.0f*(qx*qx - qz*qz);  // reference as-is
        const float R12 = 2.0f*(qy*qz - qw*qx);
        const float R20 = 2.0f*(qx*qz + qw*qy);          // reference as-is
        const float R21 = 2.0f*(qy*qz + qw*qx);
        const float R22 = 1.0f - 2.0f*(qx*qx + qy*qy);

        const float s0 = scales[3*g], s1 = scales[3*g+1], s2 = scales[3*g+2];
        const float A00 = R00*s0, A01 = R01*s1, A02 = R02*s2;
        const float A10 = R10*s0, A11 = R11*s1, A12 = R12*s2;
        const float A20 = R20*s0, A21 = R21*s1, A22 = R22*s2;
        const float S00 = A00*A00 + A01*A01 + A02*A02;
        const float S01 = A00*A10 + A01*A11 + A02*A12;
        const float S02 = A00*A20 + A01*A21 + A02*A22;
        const float S11 = A10*A10 + A11*A11 + A12*A12;
        const float S12 = A10*A20 + A11*A21 + A12*A22;
        const float S22 = A20*A20 + A21*A21 + A22*A22;

        const float tz = t2;
        const float J00 = fx / tz;
        const float J02 = -fx * t0 / (tz * tz);
        const float J11 = fy / tz;
        const float J12 = -fy * t1 / (tz * tz);
        // M = J @ Rcw (Rcw = viewmat[:3,:3])
        const float M00 = J00*vm[0] + J02*vm[8];
        const float M01 = J00*vm[1] + J02*vm[9];
        const float M02 = J00*vm[2] + J02*vm[10];
        const float M10 = J11*vm[4] + J12*vm[8];
        const float M11 = J11*vm[5] + J12*vm[9];
        const float M12 = J11*vm[6] + J12*vm[10];
        // cov = (M @ Sigma) @ M^T
        const float T00 = M00*S00 + M01*S01 + M02*S02;
        const float T01 = M00*S01 + M01*S11 + M02*S12;
        const float T02 = M00*S02 + M01*S12 + M02*S22;
        const float T10 = M10*S00 + M11*S01 + M12*S02;
        const float T11 = M10*S01 + M11*S11 + M12*S12;
        const float T12 = M10*S02 + M11*S12 + M12*S22;
        const float a   = T00*M00 + T01*M01 + T02*M02;  // cov00
        const float b   = T00*M10 + T01*M11 + T02*M12;  // cov01
        const float c10 = T10*M00 + T11*M01 + T12*M02;  // cov10
        const float d   = T10*M10 + T11*M11 + T12*M12;  // cov11

        // eigen radii (NaN-keeping sqrt)
        const float Aev = sqrtf(a*a - 2.0f*a*d + 4.0f*b*b + d*d);
        const float Bev = a + d;
        const float l1 = 0.5f * (Aev + Bev);
        const float l2 = 0.5f * (Bev - Aev);
        const float r1 = (l1 > 0.0f) ? 3.0f * sqrtf(l1) : NAN;
        const float r2 = (l2 > 0.0f) ? 3.0f * sqrtf(l2) : NAN;

        float theta;
        if (b != 0.0f) theta = atan2f(l1 - a, b);
        else           theta = (a >= d) ? (float)(3.141592653589793 / 2.0) : 0.0f;
        const float cth = cosf(theta), sth = sinf(theta);

        const float crx[4] = { mx - r1, mx + r1, mx + r1, mx - r1 };
        const float cry[4] = { my + r2, my + r2, my - r2, my - r2 };
        const float bmx = (((crx[0] + crx[1]) + crx[2]) + crx[3]) / 4.0f;
        const float bmy = (((cry[0] + cry[1]) + cry[2]) + cry[3]) / 4.0f;

        float xmn = FLT_MAX, xmxv = -FLT_MAX, ymn = FLT_MAX, ymxv = -FLT_MAX;
        #pragma unroll
        for (int k = 0; k < 4; ++k) {
            const float ox = crx[k] - bmx, oy = cry[k] - bmy;
            float bx = (cth*ox + (-sth)*oy) + bmx;
            float by = (sth*ox + cth*oy) + bmy;
            if (isnan(bx)) bx = -1.0f;
            if (isnan(by)) by = -1.0f;
            xmn = fminf(xmn, bx); xmxv = fmaxf(xmxv, bx);
            ymn = fminf(ymn, by); ymxv = fmaxf(ymxv, by);
        }
        const int Wt = Wi / TILE, Ht = Hi / TILE;
        const int xmin = (int)fminf(fmaxf(floorf(xmn  / 16.0f), 0.0f), (float)(Wt - 1));
        const int xmax = (int)fminf(fmaxf(ceilf (xmxv / 16.0f), 0.0f), (float)(Wt - 1));
        const int ymin = (int)fminf(fmaxf(floorf(ymn  / 16.0f), 0.0f), (float)(Ht - 1));
        const int ymax = (int)fminf(fmaxf(ceilf (ymxv / 16.0f), 0.0f), (float)(Ht - 1));

        // conic (inverse 2x2 with +1e-6 on diagonal; i01/i10 kept separate)
        const float e = 1e-06f;
        const float det = (a + e) * (d + e) - b * c10;
        s_i00[g] = (d + e) / det;
        s_i01[g] = -b   / det;
        s_i10[g] = -c10 / det;
        s_i11[g] = (a + e) / det;

        const float op  = opcs[g];
        const float sg1 = 1.0f / (1.0f + expf(-op));
        s_O[g] = 1.0f / (1.0f + expf(-sg1));

        s_c0[g] = fminf(fmaxf(cols[3*g    ], 1e-04f), 1.0f);
        s_c1[g] = fminf(fmaxf(cols[3*g + 1], 1e-04f), 1.0f);
        s_c2[g] = fminf(fmaxf(cols[3*g + 2], 1e-04f), 1.0f);

        s_mx[g] = mx; s_my[g] = my;
        s_bnd[g] = xmin | (xmax << 8) | (ymin << 16) | (ymax << 24);
    }

    skey[g] = key;
    sidx[g] = g;
    __syncthreads();

    // bitonic sort ascending by (key, idx)
    for (int k = 2; k <= NMAX; k <<= 1) {
        for (int j = k >> 1; j > 0; j >>= 1) {
            const int i = g;
            const int ixj = i ^ j;
            if (ixj > i) {
                const float ka = skey[i], kb = skey[ixj];
                const int   ia = sidx[i], ib = sidx[ixj];
                const bool up = ((i & k) == 0);
                const bool sw = up ? (ka > kb || (ka == kb && ia > ib))
                                   : (ka < kb || (ka == kb && ia < ib));
                if (sw) { skey[i] = kb; skey[ixj] = ka; sidx[i] = ib; sidx[ixj] = ia; }
            }
            __syncthreads();
        }
    }

    // gather sorted -> ws (SoA)
    if (g < N) {
        const int s = sidx[g];
        ws[0*NMAX + g] = s_mx[s];
        ws[1*NMAX + g] = s_my[s];
        ws[2*NMAX + g] = s_i00[s];
        ws[3*NMAX + g] = s_i01[s];
        ws[4*NMAX + g] = s_i10[s];
        ws[5*NMAX + g] = s_i11[s];
        ws[6*NMAX + g] = s_O[s];
        ws[7*NMAX + g] = s_c0[s];
        ws[8*NMAX + g] = s_c1[s];
        ws[9*NMAX + g] = s_c2[s];
        ((int*)ws)[10*NMAX + g] = s_bnd[s];
    }
}

// ---------------- Kernel 2: per-tile alpha compositing ----------------
// One block = one 16x16 tile; tile-coverage test is wave-uniform.
__global__ __launch_bounds__(256) void render_kernel(
    const float* __restrict__ ws, float* __restrict__ out, int N)
{
    __shared__ float s_mx[NMAX], s_my[NMAX];
    __shared__ float s_i00[NMAX], s_i01[NMAX], s_i10[NMAX], s_i11[NMAX];
    __shared__ float s_O[NMAX], s_c0[NMAX], s_c1[NMAX], s_c2[NMAX];
    __shared__ int   s_bnd[NMAX];

    const int lt = threadIdx.y * TILE + threadIdx.x;
    for (int i = lt; i < N; i += 256) {
        s_mx [i] = ws[0*NMAX + i];
        s_my [i] = ws[1*NMAX + i];
        s_i00[i] = ws[2*NMAX + i];
        s_i01[i] = ws[3*NMAX + i];
        s_i10[i] = ws[4*NMAX + i];
        s_i11[i] = ws[5*NMAX + i];
        s_O  [i] = ws[6*NMAX + i];
        s_c0 [i] = ws[7*NMAX + i];
        s_c1 [i] = ws[8*NMAX + i];
        s_c2 [i] = ws[9*NMAX + i];
        s_bnd[i] = ((const int*)ws)[10*NMAX + i];
    }
    __syncthreads();

    const int W  = gridDim.x * TILE;
    const int px = blockIdx.x * TILE + threadIdx.x;
    const int py = blockIdx.y * TILE + threadIdx.y;
    const int tx = blockIdx.x, ty = blockIdx.y;
    const float fpx = (float)px, fpy = (float)py;

    float Tt = 1.0f, rr = 0.0f, gg = 0.0f, bb = 0.0f;
    bool any_cover = false;

    for (int n = 0; n < N; ++n) {
        const int bnd = s_bnd[n];
        const int xmin =  bnd        & 255;
        const int xmax = (bnd >> 8)  & 255;
        const int ymin = (bnd >> 16) & 255;
        const int ymax = (bnd >> 24) & 255;
        if (tx < xmin || tx > xmax || ty < ymin || ty > ymax) continue;  // uniform
        any_cover = true;

        const float dx = fpx - s_mx[n];
        const float dy = fpy - s_my[n];
        const float quad = dx * (s_i00[n]*dx + s_i01[n]*dy)
                         + dy * (s_i10[n]*dx + s_i11[n]*dy);
        float Pg = expf(-0.5f * quad);
        if (isnan(Pg)) Pg = 0.0f;                 // nan_to_num
        float alpha = s_O[n] * Pg;
        if (alpha < 0.001f) continue;             // masked -> contributes 0, T unchanged
        alpha = fminf(alpha, 0.99f);
        const float w = alpha * Tt;
        rr += w * s_c0[n];
        gg += w * s_c1[n];
        bb += w * s_c2[n];
        Tt *= (1.0f - alpha);
    }

    const int o = (py * W + px) * 3;
    if (any_cover) {
        out[o    ] = fminf(fmaxf(rr, 1e-04f), 1.0f);
        out[o + 1] = fminf(fmaxf(gg, 1e-04f), 1.0f);
        out[o + 2] = fminf(fmaxf(bb, 1e-04f), 1.0f);
    } else {
        out[o] = 0.0f; out[o + 1] = 0.0f; out[o + 2] = 0.0f;
    }
}

extern "C" void kernel_launch(void* const* d_in, const int* in_sizes, int n_in,
                              void* d_out, int out_size, void* d_ws, size_t ws_size,
                              hipStream_t stream) {
    const float* mu     = (const float*)d_in[0];
    const float* scales = (const float*)d_in[1];
    const float* quats  = (const float*)d_in[2];
    const float* cols   = (const float*)d_in[3];
    const float* opcs   = (const float*)d_in[4];
    const float* vm     = (const float*)d_in[5];
    // d_in[6] = gt (unused by forward)
    const int* focal_p  = (const int*)d_in[7];
    const int* H_p      = (const int*)d_in[8];
    const int* W_p      = (const int*)d_in[9];

    const int N = in_sizes[4];            // opcs count = number of Gaussians
    const int HW = out_size / 3;
    int W = (int)(sqrt((double)HW) + 0.5);  // 256 for this problem
    int H = HW / W;

    float* ws = (float*)d_ws;

    prep_kernel<<<1, NMAX, 0, stream>>>(mu, scales, quats, cols, opcs, vm,
                                        focal_p, H_p, W_p, ws, N);

    dim3 grid(W / TILE, H / TILE), block(TILE, TILE);
    render_kernel<<<grid, block, 0, stream>>>(ws, (float*)d_out, N);
}

// Round 2
// 39.296 us; speedup vs baseline: 1.9349x; 1.9349x over previous
//
#include <hip/hip_runtime.h>
#include <math.h>
#include <float.h>

#define NMAX 512
#define TILE 16
#define GSTRIDE 11   // floats per Gaussian record in ws (44 B, 512*44 = 22528 B)

// ---------------- Kernel 1: per-Gaussian prep + depth sort ----------------
// One block of 512 threads. Register-resident bitonic sort: (key,idx) live in
// registers; j<=32 phases via __shfl_xor (wave64, no barrier), j>=64 via LDS.
// Output: ws AoS records in sorted depth order:
//   [0]=mx [1]=my [2]=i00 [3]=i01 [4]=i10 [5]=i11 [6]=O [7]=C0 [8]=C1 [9]=C2
//   [10]=packed tile bounds (int: xmin | xmax<<8 | ymin<<16 | ymax<<24)
__global__ __launch_bounds__(NMAX) void prep_kernel(
    const float* __restrict__ mu, const float* __restrict__ scales,
    const float* __restrict__ quats, const float* __restrict__ cols,
    const float* __restrict__ opcs, const float* __restrict__ vm,
    const int* __restrict__ focal_p, const int* __restrict__ H_p,
    const int* __restrict__ W_p, float* __restrict__ ws, int N)
{
    __shared__ float skey[NMAX];
    __shared__ int   sidx[NMAX];
    __shared__ float s_mx[NMAX], s_my[NMAX];
    __shared__ float s_i00[NMAX], s_i01[NMAX], s_i10[NMAX], s_i11[NMAX];
    __shared__ float s_O[NMAX], s_c0[NMAX], s_c1[NMAX], s_c2[NMAX];
    __shared__ int   s_bnd[NMAX];

    const int g = threadIdx.x;
    float key = FLT_MAX;

    if (g < N) {
        const int   Wi = W_p[0], Hi = H_p[0];
        const float fx = (float)focal_p[0];
        const float fy = fx;
        const float Wf = (float)Wi, Hf = (float)Hi;
        const float cxf = (float)((double)Wi / 2.0);
        const float cyf = (float)((double)Hi / 2.0);

        const float m0 = mu[3*g], m1 = mu[3*g+1], m2 = mu[3*g+2];
        const float t0 = vm[0]*m0  + vm[1]*m1  + vm[2]*m2  + vm[3];
        const float t1 = vm[4]*m0  + vm[5]*m1  + vm[6]*m2  + vm[7];
        const float t2 = vm[8]*m0  + vm[9]*m1  + vm[10]*m2 + vm[11];
        const float t3 = vm[12]*m0 + vm[13]*m1 + vm[14]*m2 + vm[15];

        const float dc1 = (float)((10.0 + 0.01) / (10.0 - 0.01));
        const float dc2 = (float)(-2.0 * 10.0 * 0.01 / (10.0 - 0.01));
        key = dc1 * t2 + dc2 * t3;

        const float sxc = (float)(2.0 * (double)fx / (double)Wi);
        const float syc = (float)(2.0 * (double)fy / (double)Hi);
        const float tp0 = sxc * t0;
        const float tp1 = syc * t1;
        const float mx = Wf * tp0 / t2 / 2.0f + cxf;
        const float my = Hf * tp1 / t2 / 2.0f + cyf;

        // quaternion -> R  (reference's exact formulas incl. its r11/r20 quirks)
        const float qx = quats[4*g], qy = quats[4*g+1], qz = quats[4*g+2], qw = quats[4*g+3];
        const float R00 = 1.0f - 2.0f*(qy*qy + qz*qz);
        const float R01 = 2.0f*(qx*qy - qw*qz);
        const float R02 = 2.0f*(qx*qz + qw*qy);
        const float R10 = 2.0f*(qx*qy + qw*qz);
        const float R11 = 1.0f - 2.0f*(qx*qx - qz*qz);
        const float R12 = 2.0f*(qy*qz - qw*qx);
        const float R20 = 2.0f*(qx*qz + qw*qy);
        const float R21 = 2.0f*(qy*qz + qw*qx);
        const float R22 = 1.0f - 2.0f*(qx*qx + qy*qy);

        const float s0 = scales[3*g], s1 = scales[3*g+1], s2 = scales[3*g+2];
        const float A00 = R00*s0, A01 = R01*s1, A02 = R02*s2;
        const float A10 = R10*s0, A11 = R11*s1, A12 = R12*s2;
        const float A20 = R20*s0, A21 = R21*s1, A22 = R22*s2;
        const float S00 = A00*A00 + A01*A01 + A02*A02;
        const float S01 = A00*A10 + A01*A11 + A02*A12;
        const float S02 = A00*A20 + A01*A21 + A02*A22;
        const float S11 = A10*A10 + A11*A11 + A12*A12;
        const float S12 = A10*A20 + A11*A21 + A12*A22;
        const float S22 = A20*A20 + A21*A21 + A22*A22;

        const float tz = t2;
        const float J00 = fx / tz;
        const float J02 = -fx * t0 / (tz * tz);
        const float J11 = fy / tz;
        const float J12 = -fy * t1 / (tz * tz);
        const float M00 = J00*vm[0] + J02*vm[8];
        const float M01 = J00*vm[1] + J02*vm[9];
        const float M02 = J00*vm[2] + J02*vm[10];
        const float M10 = J11*vm[4] + J12*vm[8];
        const float M11 = J11*vm[5] + J12*vm[9];
        const float M12 = J11*vm[6] + J12*vm[10];
        const float T00 = M00*S00 + M01*S01 + M02*S02;
        const float T01 = M00*S01 + M01*S11 + M02*S12;
        const float T02 = M00*S02 + M01*S12 + M02*S22;
        const float T10 = M10*S00 + M11*S01 + M12*S02;
        const float T11 = M10*S01 + M11*S11 + M12*S12;
        const float T12 = M10*S02 + M11*S12 + M12*S22;
        const float a   = T00*M00 + T01*M01 + T02*M02;
        const float b   = T00*M10 + T01*M11 + T02*M12;
        const float c10 = T10*M00 + T11*M01 + T12*M02;
        const float d   = T10*M10 + T11*M11 + T12*M12;

        const float Aev = sqrtf(a*a - 2.0f*a*d + 4.0f*b*b + d*d);
        const float Bev = a + d;
        const float l1 = 0.5f * (Aev + Bev);
        const float l2 = 0.5f * (Bev - Aev);
        const float r1 = (l1 > 0.0f) ? 3.0f * sqrtf(l1) : NAN;
        const float r2 = (l2 > 0.0f) ? 3.0f * sqrtf(l2) : NAN;

        float theta;
        if (b != 0.0f) theta = atan2f(l1 - a, b);
        else           theta = (a >= d) ? (float)(3.141592653589793 / 2.0) : 0.0f;
        const float cth = cosf(theta), sth = sinf(theta);

        const float crx[4] = { mx - r1, mx + r1, mx + r1, mx - r1 };
        const float cry[4] = { my + r2, my + r2, my - r2, my - r2 };
        const float bmx = (((crx[0] + crx[1]) + crx[2]) + crx[3]) / 4.0f;
        const float bmy = (((cry[0] + cry[1]) + cry[2]) + cry[3]) / 4.0f;

        float xmn = FLT_MAX, xmxv = -FLT_MAX, ymn = FLT_MAX, ymxv = -FLT_MAX;
        #pragma unroll
        for (int k = 0; k < 4; ++k) {
            const float ox = crx[k] - bmx, oy = cry[k] - bmy;
            float bx = (cth*ox + (-sth)*oy) + bmx;
            float by = (sth*ox + cth*oy) + bmy;
            if (isnan(bx)) bx = -1.0f;
            if (isnan(by)) by = -1.0f;
            xmn = fminf(xmn, bx); xmxv = fmaxf(xmxv, bx);
            ymn = fminf(ymn, by); ymxv = fmaxf(ymxv, by);
        }
        const int Wt = Wi / TILE, Ht = Hi / TILE;
        const int xmin = (int)fminf(fmaxf(floorf(xmn  / 16.0f), 0.0f), (float)(Wt - 1));
        const int xmax = (int)fminf(fmaxf(ceilf (xmxv / 16.0f), 0.0f), (float)(Wt - 1));
        const int ymin = (int)fminf(fmaxf(floorf(ymn  / 16.0f), 0.0f), (float)(Ht - 1));
        const int ymax = (int)fminf(fmaxf(ceilf (ymxv / 16.0f), 0.0f), (float)(Ht - 1));

        const float e = 1e-06f;
        const float det = (a + e) * (d + e) - b * c10;
        s_i00[g] = (d + e) / det;
        s_i01[g] = -b   / det;
        s_i10[g] = -c10 / det;
        s_i11[g] = (a + e) / det;

        const float op  = opcs[g];
        const float sg1 = 1.0f / (1.0f + expf(-op));
        s_O[g] = 1.0f / (1.0f + expf(-sg1));

        s_c0[g] = fminf(fmaxf(cols[3*g    ], 1e-04f), 1.0f);
        s_c1[g] = fminf(fmaxf(cols[3*g + 1], 1e-04f), 1.0f);
        s_c2[g] = fminf(fmaxf(cols[3*g + 2], 1e-04f), 1.0f);

        s_mx[g] = mx; s_my[g] = my;
        s_bnd[g] = xmin | (xmax << 8) | (ymin << 16) | (ymax << 24);
    }

    // ---- register-resident bitonic sort ascending by (key, idx) ----
    int idx = g;
    const int i = g;
    for (int k = 2; k <= NMAX; k <<= 1) {
        for (int j = k >> 1; j > 0; j >>= 1) {
            float ok; int oi;
            if (j >= 64) {                      // cross-wave: LDS exchange
                skey[i] = key; sidx[i] = idx;
                __syncthreads();
                ok = skey[i ^ j]; oi = sidx[i ^ j];
                __syncthreads();
            } else {                            // intra-wave: shuffle
                ok = __shfl_xor(key, j, 64);
                oi = __shfl_xor(idx, j, 64);
            }
            const bool up = ((i & k) == 0);
            const bool keep_small = (((i & j) == 0) == up);
            const bool less = (ok < key) || (ok == key && oi < idx);
            if (keep_small ? less : !less) { key = ok; idx = oi; }
        }
    }
    __syncthreads();   // ensure s_* arrays fully written (also orders vs sort LDS reuse)

    // gather sorted -> ws (AoS, 11 floats per record)
    if (g < N) {
        const int s = idx;
        float* p = ws + g * GSTRIDE;
        p[0] = s_mx[s];  p[1] = s_my[s];
        p[2] = s_i00[s]; p[3] = s_i01[s]; p[4] = s_i10[s]; p[5] = s_i11[s];
        p[6] = s_O[s];
        p[7] = s_c0[s];  p[8] = s_c1[s];  p[9] = s_c2[s];
        ((int*)p)[10] = s_bnd[s];
    }
}

// ---------------- Kernel 2: per-tile ballot-compacted compositing ----------------
// One block = one 16x16 tile. Wave ballots build an 8-word coverage bitmask
// (bit order == sorted order); composite loop visits only set bits.
__global__ __launch_bounds__(256) void render_kernel(
    const float* __restrict__ ws, float* __restrict__ out, int N)
{
    __shared__ unsigned long long masks[8];

    const int lt  = threadIdx.y * TILE + threadIdx.x;
    const int wid = lt >> 6;
    const int tx  = blockIdx.x, ty = blockIdx.y;

    // coverage test for n = lt and n = lt + 256 (tile test is identical for
    // all threads in the block; ballot bit l of wave w corresponds to n=w*64+l)
    auto covers = [&](int n) -> bool {
        if (n >= N) return false;
        const int bnd = ((const int*)ws)[n * GSTRIDE + 10];
        const int xmin =  bnd        & 255;
        const int xmax = (bnd >> 8)  & 255;
        const int ymin = (bnd >> 16) & 255;
        const int ymax = (bnd >> 24) & 255;
        return (tx >= xmin) & (tx <= xmax) & (ty >= ymin) & (ty <= ymax);
    };
    const unsigned long long b0 = __ballot(covers(lt));
    const unsigned long long b1 = __ballot(covers(lt + 256));
    if ((lt & 63) == 0) { masks[wid] = b0; masks[4 + wid] = b1; }
    __syncthreads();

    const int W  = gridDim.x * TILE;
    const int px = blockIdx.x * TILE + threadIdx.x;
    const int py = blockIdx.y * TILE + threadIdx.y;
    const float fpx = (float)px, fpy = (float)py;

    float Tt = 1.0f, rr = 0.0f, gg = 0.0f, bb = 0.0f;
    bool any_cover = false;

    #pragma unroll
    for (int w = 0; w < 8; ++w) {
        unsigned long long m = masks[w];
        if (m) any_cover = true;
        while (m) {
            const int l = __builtin_ctzll(m);
            m &= m - 1;
            const int n = w * 64 + l;
            const float* p = ws + n * GSTRIDE;
            const float mxv = p[0], myv = p[1];
            const float i00 = p[2], i01 = p[3], i10 = p[4], i11 = p[5];
            const float O   = p[6];
            const float c0  = p[7], c1 = p[8], c2 = p[9];

            const float dx = fpx - mxv;
            const float dy = fpy - myv;
            const float quad = dx * (i00*dx + i01*dy) + dy * (i10*dx + i11*dy);
            float Pg = expf(-0.5f * quad);
            if (isnan(Pg)) Pg = 0.0f;                  // nan_to_num
            float alpha = O * Pg;
            if (alpha < 0.001f) continue;              // below threshold: T unchanged
            alpha = fminf(alpha, 0.99f);
            const float wgt = alpha * Tt;
            rr += wgt * c0;
            gg += wgt * c1;
            bb += wgt * c2;
            Tt *= (1.0f - alpha);
        }
    }

    const int o = (py * W + px) * 3;
    if (any_cover) {
        out[o    ] = fminf(fmaxf(rr, 1e-04f), 1.0f);
        out[o + 1] = fminf(fmaxf(gg, 1e-04f), 1.0f);
        out[o + 2] = fminf(fmaxf(bb, 1e-04f), 1.0f);
    } else {
        out[o] = 0.0f; out[o + 1] = 0.0f; out[o + 2] = 0.0f;
    }
}

extern "C" void kernel_launch(void* const* d_in, const int* in_sizes, int n_in,
                              void* d_out, int out_size, void* d_ws, size_t ws_size,
                              hipStream_t stream) {
    const float* mu     = (const float*)d_in[0];
    const float* scales = (const float*)d_in[1];
    const float* quats  = (const float*)d_in[2];
    const float* cols   = (const float*)d_in[3];
    const float* opcs   = (const float*)d_in[4];
    const float* vm     = (const float*)d_in[5];
    // d_in[6] = gt (unused by forward)
    const int* focal_p  = (const int*)d_in[7];
    const int* H_p      = (const int*)d_in[8];
    const int* W_p      = (const int*)d_in[9];

    const int N = in_sizes[4];              // opcs count = number of Gaussians
    const int HW = out_size / 3;
    int W = (int)(sqrt((double)HW) + 0.5);  // 256 for this problem
    int H = HW / W;

    float* ws = (float*)d_ws;

    prep_kernel<<<1, NMAX, 0, stream>>>(mu, scales, quats, cols, opcs, vm,
                                        focal_p, H_p, W_p, ws, N);

    dim3 grid(W / TILE, H / TILE), block(TILE, TILE);
    render_kernel<<<grid, block, 0, stream>>>(ws, (float*)d_out, N);
}

// Round 3
// 26.054 us; speedup vs baseline: 2.9184x; 1.5083x over previous
//
#include <hip/hip_runtime.h>
#include <math.h>
#include <float.h>

#define NMAX 512
#define TILE 16

// Fully fused: each block = one 16x16 tile. The block re-computes per-Gaussian
// prep for ALL N Gaussians into LDS (2/thread), tests tile coverage, compacts
// the covered subset, rank-sorts it by (depth,idx) -- equivalent to the global
// stable argsort restricted to the subset -- then alpha-composites.
__global__ __launch_bounds__(256) void fused_kernel(
    const float* __restrict__ mu, const float* __restrict__ scales,
    const float* __restrict__ quats, const float* __restrict__ cols,
    const float* __restrict__ opcs, const float* __restrict__ vm,
    const int* __restrict__ focal_p, const int* __restrict__ H_p,
    const int* __restrict__ W_p, float* __restrict__ out, int N)
{
    __shared__ float s_mx[NMAX], s_my[NMAX];
    __shared__ float s_i00[NMAX], s_i01[NMAX], s_i10[NMAX], s_i11[NMAX];
    __shared__ float s_O[NMAX], s_c0[NMAX], s_c1[NMAX], s_c2[NMAX];
    __shared__ unsigned int s_key[NMAX];          // order-preserving depth bits
    __shared__ int s_list[NMAX];                  // covered indices (unordered)
    __shared__ unsigned long long s_lk[NMAX];     // combined (key,idx) for rank sort
    __shared__ int s_sorted[NMAX];
    __shared__ int s_cnt;

    const int lt = threadIdx.y * TILE + threadIdx.x;
    const int tx = blockIdx.x, ty = blockIdx.y;

    if (lt == 0) s_cnt = 0;
    __syncthreads();

    const int   Wi = W_p[0], Hi = H_p[0];
    const float fx = (float)focal_p[0];
    const float fy = fx;
    const float Wf = (float)Wi, Hf = (float)Hi;
    const float cxf = (float)((double)Wi / 2.0);
    const float cyf = (float)((double)Hi / 2.0);
    const float sxc = (float)(2.0 * (double)fx / (double)Wi);
    const float syc = (float)(2.0 * (double)fy / (double)Hi);
    const float dc1 = (float)((10.0 + 0.01) / (10.0 - 0.01));
    const float dc2 = (float)(-2.0 * 10.0 * 0.01 / (10.0 - 0.01));
    const int Wt = Wi / TILE, Ht = Hi / TILE;

    // ---- prep (2 Gaussians per thread) + coverage append ----
    for (int rep = 0; rep < 2; ++rep) {
        const int g = lt + rep * 256;
        if (g >= N) continue;

        const float m0 = mu[3*g], m1 = mu[3*g+1], m2 = mu[3*g+2];
        const float t0 = vm[0]*m0  + vm[1]*m1  + vm[2]*m2  + vm[3];
        const float t1 = vm[4]*m0  + vm[5]*m1  + vm[6]*m2  + vm[7];
        const float t2 = vm[8]*m0  + vm[9]*m1  + vm[10]*m2 + vm[11];
        const float t3 = vm[12]*m0 + vm[13]*m1 + vm[14]*m2 + vm[15];

        const float depth = dc1 * t2 + dc2 * t3;
        unsigned int ub = __float_as_uint(depth);
        ub = (ub & 0x80000000u) ? ~ub : (ub | 0x80000000u);
        s_key[g] = ub;

        const float tp0 = sxc * t0;
        const float tp1 = syc * t1;
        const float mx = Wf * tp0 / t2 / 2.0f + cxf;
        const float my = Hf * tp1 / t2 / 2.0f + cyf;

        // quaternion -> R (reference's exact formulas incl. its r11/r20 quirks)
        const float qx = quats[4*g], qy = quats[4*g+1], qz = quats[4*g+2], qw = quats[4*g+3];
        const float R00 = 1.0f - 2.0f*(qy*qy + qz*qz);
        const float R01 = 2.0f*(qx*qy - qw*qz);
        const float R02 = 2.0f*(qx*qz + qw*qy);
        const float R10 = 2.0f*(qx*qy + qw*qz);
        const float R11 = 1.0f - 2.0f*(qx*qx - qz*qz);
        const float R12 = 2.0f*(qy*qz - qw*qx);
        const float R20 = 2.0f*(qx*qz + qw*qy);
        const float R21 = 2.0f*(qy*qz + qw*qx);
        const float R22 = 1.0f - 2.0f*(qx*qx + qy*qy);

        const float s0 = scales[3*g], s1 = scales[3*g+1], s2 = scales[3*g+2];
        const float A00 = R00*s0, A01 = R01*s1, A02 = R02*s2;
        const float A10 = R10*s0, A11 = R11*s1, A12 = R12*s2;
        const float A20 = R20*s0, A21 = R21*s1, A22 = R22*s2;
        const float S00 = A00*A00 + A01*A01 + A02*A02;
        const float S01 = A00*A10 + A01*A11 + A02*A12;
        const float S02 = A00*A20 + A01*A21 + A02*A22;
        const float S11 = A10*A10 + A11*A11 + A12*A12;
        const float S12 = A10*A20 + A11*A21 + A12*A22;
        const float S22 = A20*A20 + A21*A21 + A22*A22;

        const float tz = t2;
        const float J00 = fx / tz;
        const float J02 = -fx * t0 / (tz * tz);
        const float J11 = fy / tz;
        const float J12 = -fy * t1 / (tz * tz);
        const float M00 = J00*vm[0] + J02*vm[8];
        const float M01 = J00*vm[1] + J02*vm[9];
        const float M02 = J00*vm[2] + J02*vm[10];
        const float M10 = J11*vm[4] + J12*vm[8];
        const float M11 = J11*vm[5] + J12*vm[9];
        const float M12 = J11*vm[6] + J12*vm[10];
        const float T00 = M00*S00 + M01*S01 + M02*S02;
        const float T01 = M00*S01 + M01*S11 + M02*S12;
        const float T02 = M00*S02 + M01*S12 + M02*S22;
        const float T10 = M10*S00 + M11*S01 + M12*S02;
        const float T11 = M10*S01 + M11*S11 + M12*S12;
        const float T12 = M10*S02 + M11*S12 + M12*S22;
        const float a   = T00*M00 + T01*M01 + T02*M02;
        const float b   = T00*M10 + T01*M11 + T02*M12;
        const float c10 = T10*M00 + T11*M01 + T12*M02;
        const float d   = T10*M10 + T11*M11 + T12*M12;

        const float Aev = sqrtf(a*a - 2.0f*a*d + 4.0f*b*b + d*d);
        const float Bev = a + d;
        const float l1 = 0.5f * (Aev + Bev);
        const float l2 = 0.5f * (Bev - Aev);
        const float r1 = (l1 > 0.0f) ? 3.0f * sqrtf(l1) : NAN;
        const float r2 = (l2 > 0.0f) ? 3.0f * sqrtf(l2) : NAN;

        float theta;
        if (b != 0.0f) theta = atan2f(l1 - a, b);
        else           theta = (a >= d) ? (float)(3.141592653589793 / 2.0) : 0.0f;
        const float cth = cosf(theta), sth = sinf(theta);

        const float crx[4] = { mx - r1, mx + r1, mx + r1, mx - r1 };
        const float cry[4] = { my + r2, my + r2, my - r2, my - r2 };
        const float bmx = (((crx[0] + crx[1]) + crx[2]) + crx[3]) / 4.0f;
        const float bmy = (((cry[0] + cry[1]) + cry[2]) + cry[3]) / 4.0f;

        float xmn = FLT_MAX, xmxv = -FLT_MAX, ymn = FLT_MAX, ymxv = -FLT_MAX;
        #pragma unroll
        for (int k = 0; k < 4; ++k) {
            const float ox = crx[k] - bmx, oy = cry[k] - bmy;
            float bx = (cth*ox + (-sth)*oy) + bmx;
            float by = (sth*ox + cth*oy) + bmy;
            if (isnan(bx)) bx = -1.0f;
            if (isnan(by)) by = -1.0f;
            xmn = fminf(xmn, bx); xmxv = fmaxf(xmxv, bx);
            ymn = fminf(ymn, by); ymxv = fmaxf(ymxv, by);
        }
        const int xmin = (int)fminf(fmaxf(floorf(xmn  / 16.0f), 0.0f), (float)(Wt - 1));
        const int xmax = (int)fminf(fmaxf(ceilf (xmxv / 16.0f), 0.0f), (float)(Wt - 1));
        const int ymin = (int)fminf(fmaxf(floorf(ymn  / 16.0f), 0.0f), (float)(Ht - 1));
        const int ymax = (int)fminf(fmaxf(ceilf (ymxv / 16.0f), 0.0f), (float)(Ht - 1));

        const float e = 1e-06f;
        const float det = (a + e) * (d + e) - b * c10;
        s_i00[g] = (d + e) / det;
        s_i01[g] = -b   / det;
        s_i10[g] = -c10 / det;
        s_i11[g] = (a + e) / det;

        const float op  = opcs[g];
        const float sg1 = 1.0f / (1.0f + expf(-op));
        s_O[g] = 1.0f / (1.0f + expf(-sg1));

        s_c0[g] = fminf(fmaxf(cols[3*g    ], 1e-04f), 1.0f);
        s_c1[g] = fminf(fmaxf(cols[3*g + 1], 1e-04f), 1.0f);
        s_c2[g] = fminf(fmaxf(cols[3*g + 2], 1e-04f), 1.0f);
        s_mx[g] = mx; s_my[g] = my;

        // coverage of THIS tile (block-uniform test per Gaussian)
        if (tx >= xmin && tx <= xmax && ty >= ymin && ty <= ymax) {
            const int pos = atomicAdd(&s_cnt, 1);
            s_list[pos] = g;
        }
    }
    __syncthreads();
    const int M = s_cnt;

    // ---- deterministic rank sort of covered subset by (depth key, idx) ----
    for (int t = lt; t < M; t += 256) {
        const int g = s_list[t];
        s_lk[t] = ((unsigned long long)s_key[g] << 32) | (unsigned int)g;
    }
    __syncthreads();
    for (int t = lt; t < M; t += 256) {
        const unsigned long long mine = s_lk[t];
        int rank = 0;
        for (int s = 0; s < M; ++s) rank += (s_lk[s] < mine) ? 1 : 0;
        s_sorted[rank] = (int)(mine & 0xFFFFFFFFu);
    }
    __syncthreads();

    // ---- alpha compositing, front to back ----
    const int W  = gridDim.x * TILE;
    const int px = blockIdx.x * TILE + threadIdx.x;
    const int py = blockIdx.y * TILE + threadIdx.y;
    const float fpx = (float)px, fpy = (float)py;

    float Tt = 1.0f, rr = 0.0f, gg = 0.0f, bb = 0.0f;

    for (int j = 0; j < M; ++j) {
        const int n = s_sorted[j];
        const float dx = fpx - s_mx[n];
        const float dy = fpy - s_my[n];
        const float quad = dx * (s_i00[n]*dx + s_i01[n]*dy)
                         + dy * (s_i10[n]*dx + s_i11[n]*dy);
        float Pg = expf(-0.5f * quad);
        if (isnan(Pg)) Pg = 0.0f;                 // nan_to_num
        float alpha = s_O[n] * Pg;
        if (alpha < 0.001f) continue;             // below threshold: T unchanged
        alpha = fminf(alpha, 0.99f);
        const float wgt = alpha * Tt;
        rr += wgt * s_c0[n];
        gg += wgt * s_c1[n];
        bb += wgt * s_c2[n];
        Tt *= (1.0f - alpha);
    }

    const int o = (py * W + px) * 3;
    if (M > 0) {
        out[o    ] = fminf(fmaxf(rr, 1e-04f), 1.0f);
        out[o + 1] = fminf(fmaxf(gg, 1e-04f), 1.0f);
        out[o + 2] = fminf(fmaxf(bb, 1e-04f), 1.0f);
    } else {
        out[o] = 0.0f; out[o + 1] = 0.0f; out[o + 2] = 0.0f;
    }
}

extern "C" void kernel_launch(void* const* d_in, const int* in_sizes, int n_in,
                              void* d_out, int out_size, void* d_ws, size_t ws_size,
                              hipStream_t stream) {
    const float* mu     = (const float*)d_in[0];
    const float* scales = (const float*)d_in[1];
    const float* quats  = (const float*)d_in[2];
    const float* cols   = (const float*)d_in[3];
    const float* opcs   = (const float*)d_in[4];
    const float* vm     = (const float*)d_in[5];
    // d_in[6] = gt (unused by forward)
    const int* focal_p  = (const int*)d_in[7];
    const int* H_p      = (const int*)d_in[8];
    const int* W_p      = (const int*)d_in[9];

    const int N = in_sizes[4];              // opcs count = number of Gaussians
    const int HW = out_size / 3;
    int W = (int)(sqrt((double)HW) + 0.5);  // 256 for this problem
    int H = HW / W;

    dim3 grid(W / TILE, H / TILE), block(TILE, TILE);
    fused_kernel<<<grid, block, 0, stream>>>(mu, scales, quats, cols, opcs, vm,
                                             focal_p, H_p, W_p, (float*)d_out, N);
}

// Round 4
// 17.601 us; speedup vs baseline: 4.3199x; 1.4803x over previous
//
#include <hip/hip_runtime.h>
#include <math.h>
#include <float.h>

#define NMAX 512
#define TILE 16
#define FDIV(a,b) __fdividef((a),(b))

// Fully fused, 512 threads/block, one block per 16x16 tile.
// Phase 1: each thread preps ONE Gaussian (fast-math transcendentals) into LDS,
//          tests tile coverage, appends covered index.
// Phase 2: deterministic rank-sort of covered subset by (depth-key, idx)
//          == global stable argsort restricted to the subset.
// Phase 3: alpha compositing split across two thread-halves per pixel
//          (compositing is associative: C = C0 + T0*C1), combined via LDS.
__global__ __launch_bounds__(512) void fused_kernel(
    const float* __restrict__ mu, const float* __restrict__ scales,
    const float* __restrict__ quats, const float* __restrict__ cols,
    const float* __restrict__ opcs, const float* __restrict__ vm,
    const int* __restrict__ focal_p, const int* __restrict__ H_p,
    const int* __restrict__ W_p, float* __restrict__ out, int N)
{
    __shared__ float s_mx[NMAX], s_my[NMAX];
    __shared__ float s_i00[NMAX], s_i01[NMAX], s_i10[NMAX], s_i11[NMAX];
    __shared__ float s_O[NMAX], s_c0[NMAX], s_c1[NMAX], s_c2[NMAX];
    __shared__ unsigned int s_key[NMAX];        // order-preserving depth bits
    __shared__ int s_list[NMAX];                // covered indices (unordered)
    __shared__ unsigned long long s_lk[NMAX];   // (key<<32)|idx for rank sort
    __shared__ int s_sorted[NMAX];
    __shared__ float s_pr[256], s_pg[256], s_pb[256], s_pT[256];
    __shared__ int s_cnt;

    const int lt = threadIdx.x;       // 0..511
    const int p  = lt & 255;          // pixel within tile
    const int hv = lt >> 8;           // half index 0/1
    const int tx = blockIdx.x, ty = blockIdx.y;

    if (lt == 0) s_cnt = 0;
    __syncthreads();

    const int   Wi = W_p[0], Hi = H_p[0];
    const float fx = (float)focal_p[0];
    const float fy = fx;
    const float Wf = (float)Wi, Hf = (float)Hi;
    const float cxf = (float)((double)Wi / 2.0);
    const float cyf = (float)((double)Hi / 2.0);
    const float sxc = (float)(2.0 * (double)fx / (double)Wi);
    const float syc = (float)(2.0 * (double)fy / (double)Hi);
    const float dc1 = (float)((10.0 + 0.01) / (10.0 - 0.01));
    const float dc2 = (float)(-2.0 * 10.0 * 0.01 / (10.0 - 0.01));
    const int Wt = Wi / TILE, Ht = Hi / TILE;

    // ---- phase 1: prep (1 Gaussian per thread) + coverage append ----
    const int g = lt;
    if (g < N) {
        const float m0 = mu[3*g], m1 = mu[3*g+1], m2 = mu[3*g+2];
        const float t0 = vm[0]*m0  + vm[1]*m1  + vm[2]*m2  + vm[3];
        const float t1 = vm[4]*m0  + vm[5]*m1  + vm[6]*m2  + vm[7];
        const float t2 = vm[8]*m0  + vm[9]*m1  + vm[10]*m2 + vm[11];
        const float t3 = vm[12]*m0 + vm[13]*m1 + vm[14]*m2 + vm[15];

        const float depth = dc1 * t2 + dc2 * t3;
        unsigned int ub = __float_as_uint(depth);
        ub = (ub & 0x80000000u) ? ~ub : (ub | 0x80000000u);
        s_key[g] = ub;

        const float mx = FDIV(Wf * (sxc * t0), t2) * 0.5f + cxf;
        const float my = FDIV(Hf * (syc * t1), t2) * 0.5f + cyf;

        // quaternion -> R (reference's exact formulas incl. its r11/r20 quirks)
        const float4 q = ((const float4*)quats)[g];
        const float qx = q.x, qy = q.y, qz = q.z, qw = q.w;
        const float R00 = 1.0f - 2.0f*(qy*qy + qz*qz);
        const float R01 = 2.0f*(qx*qy - qw*qz);
        const float R02 = 2.0f*(qx*qz + qw*qy);
        const float R10 = 2.0f*(qx*qy + qw*qz);
        const float R11 = 1.0f - 2.0f*(qx*qx - qz*qz);
        const float R12 = 2.0f*(qy*qz - qw*qx);
        const float R20 = 2.0f*(qx*qz + qw*qy);
        const float R21 = 2.0f*(qy*qz + qw*qx);
        const float R22 = 1.0f - 2.0f*(qx*qx + qy*qy);

        const float s0 = scales[3*g], s1 = scales[3*g+1], s2 = scales[3*g+2];
        const float A00 = R00*s0, A01 = R01*s1, A02 = R02*s2;
        const float A10 = R10*s0, A11 = R11*s1, A12 = R12*s2;
        const float A20 = R20*s0, A21 = R21*s1, A22 = R22*s2;
        const float S00 = A00*A00 + A01*A01 + A02*A02;
        const float S01 = A00*A10 + A01*A11 + A02*A12;
        const float S02 = A00*A20 + A01*A21 + A02*A22;
        const float S11 = A10*A10 + A11*A11 + A12*A12;
        const float S12 = A10*A20 + A11*A21 + A12*A22;
        const float S22 = A20*A20 + A21*A21 + A22*A22;

        const float tz = t2;
        const float J00 = FDIV(fx, tz);
        const float J02 = FDIV(-fx * t0, tz * tz);
        const float J11 = FDIV(fy, tz);
        const float J12 = FDIV(-fy * t1, tz * tz);
        const float M00 = J00*vm[0] + J02*vm[8];
        const float M01 = J00*vm[1] + J02*vm[9];
        const float M02 = J00*vm[2] + J02*vm[10];
        const float M10 = J11*vm[4] + J12*vm[8];
        const float M11 = J11*vm[5] + J12*vm[9];
        const float M12 = J11*vm[6] + J12*vm[10];
        const float T00 = M00*S00 + M01*S01 + M02*S02;
        const float T01 = M00*S01 + M01*S11 + M02*S12;
        const float T02 = M00*S02 + M01*S12 + M02*S22;
        const float T10 = M10*S00 + M11*S01 + M12*S02;
        const float T11 = M10*S01 + M11*S11 + M12*S12;
        const float T12 = M10*S02 + M11*S12 + M12*S22;
        const float a   = T00*M00 + T01*M01 + T02*M02;
        const float b   = T00*M10 + T01*M11 + T02*M12;
        const float c10 = T10*M00 + T11*M01 + T12*M02;
        const float d   = T10*M10 + T11*M11 + T12*M12;

        const float Aev = sqrtf(a*a - 2.0f*a*d + 4.0f*b*b + d*d);
        const float Bev = a + d;
        const float l1 = 0.5f * (Aev + Bev);
        const float l2 = 0.5f * (Bev - Aev);
        const float r1 = (l1 > 0.0f) ? 3.0f * sqrtf(l1) : NAN;
        const float r2 = (l2 > 0.0f) ? 3.0f * sqrtf(l2) : NAN;

        // cos/sin of atan2(l1-a, b) computed algebraically
        float cth, sth;
        if (b != 0.0f) {
            const float yv = l1 - a;
            const float h  = sqrtf(b*b + yv*yv);     // > 0 since b != 0
            cth = FDIV(b,  h);
            sth = FDIV(yv, h);
        } else if (a >= d) {
            cth = -4.371139e-8f;   // cosf(pi/2 as float)
            sth = 1.0f;            // sinf(pi/2 as float)
        } else {
            cth = 1.0f;
            sth = 0.0f;
        }

        const float crx[4] = { mx - r1, mx + r1, mx + r1, mx - r1 };
        const float cry[4] = { my + r2, my + r2, my - r2, my - r2 };
        const float bmx = (((crx[0] + crx[1]) + crx[2]) + crx[3]) * 0.25f;
        const float bmy = (((cry[0] + cry[1]) + cry[2]) + cry[3]) * 0.25f;

        float xmn = FLT_MAX, xmxv = -FLT_MAX, ymn = FLT_MAX, ymxv = -FLT_MAX;
        #pragma unroll
        for (int k = 0; k < 4; ++k) {
            const float ox = crx[k] - bmx, oy = cry[k] - bmy;
            float bx = (cth*ox + (-sth)*oy) + bmx;
            float by = (sth*ox + cth*oy) + bmy;
            if (isnan(bx)) bx = -1.0f;
            if (isnan(by)) by = -1.0f;
            xmn = fminf(xmn, bx); xmxv = fmaxf(xmxv, bx);
            ymn = fminf(ymn, by); ymxv = fmaxf(ymxv, by);
        }
        const int xmin = (int)fminf(fmaxf(floorf(xmn  * 0.0625f), 0.0f), (float)(Wt - 1));
        const int xmax = (int)fminf(fmaxf(ceilf (xmxv * 0.0625f), 0.0f), (float)(Wt - 1));
        const int ymin = (int)fminf(fmaxf(floorf(ymn  * 0.0625f), 0.0f), (float)(Ht - 1));
        const int ymax = (int)fminf(fmaxf(ceilf (ymxv * 0.0625f), 0.0f), (float)(Ht - 1));

        const float e = 1e-06f;
        const float det = (a + e) * (d + e) - b * c10;
        const float idet = FDIV(1.0f, det);
        s_i00[g] = (d + e) * idet;
        s_i01[g] = -b   * idet;
        s_i10[g] = -c10 * idet;
        s_i11[g] = (a + e) * idet;

        const float op  = opcs[g];
        const float sg1 = FDIV(1.0f, 1.0f + __expf(-op));
        s_O[g] = FDIV(1.0f, 1.0f + __expf(-sg1));

        s_c0[g] = fminf(fmaxf(cols[3*g    ], 1e-04f), 1.0f);
        s_c1[g] = fminf(fmaxf(cols[3*g + 1], 1e-04f), 1.0f);
        s_c2[g] = fminf(fmaxf(cols[3*g + 2], 1e-04f), 1.0f);
        s_mx[g] = mx; s_my[g] = my;

        if (tx >= xmin && tx <= xmax && ty >= ymin && ty <= ymax) {
            const int pos = atomicAdd(&s_cnt, 1);
            s_list[pos] = g;
        }
    }
    __syncthreads();
    const int M = s_cnt;

    // ---- phase 2: deterministic rank sort of covered subset ----
    for (int t = lt; t < M; t += 512) {
        const int gi = s_list[t];
        s_lk[t] = ((unsigned long long)s_key[gi] << 32) | (unsigned int)gi;
    }
    __syncthreads();
    for (int t = lt; t < M; t += 512) {
        const unsigned long long mine = s_lk[t];
        int rank = 0;
        for (int s = 0; s < M; ++s) rank += (s_lk[s] < mine) ? 1 : 0;
        s_sorted[rank] = (int)(mine & 0xFFFFFFFFu);
    }
    __syncthreads();

    // ---- phase 3: split alpha compositing (front half / back half) ----
    const int W  = gridDim.x * TILE;
    const int px = tx * TILE + (p & 15);
    const int py = ty * TILE + (p >> 4);
    const float fpx = (float)px, fpy = (float)py;

    const int Mh = (M + 1) >> 1;
    const int j0 = hv ? Mh : 0;
    const int j1 = hv ? M  : Mh;

    float Tt = 1.0f, rr = 0.0f, gg = 0.0f, bb = 0.0f;
    for (int j = j0; j < j1; ++j) {
        const int n = s_sorted[j];
        const float dx = fpx - s_mx[n];
        const float dy = fpy - s_my[n];
        const float quad = dx * (s_i00[n]*dx + s_i01[n]*dy)
                         + dy * (s_i10[n]*dx + s_i11[n]*dy);
        float Pg = __expf(-0.5f * quad);
        if (isnan(Pg)) Pg = 0.0f;                 // nan_to_num
        float alpha = s_O[n] * Pg;
        if (alpha < 0.001f) continue;             // below threshold: T unchanged
        alpha = fminf(alpha, 0.99f);
        const float wgt = alpha * Tt;
        rr += wgt * s_c0[n];
        gg += wgt * s_c1[n];
        bb += wgt * s_c2[n];
        Tt *= (1.0f - alpha);
    }

    if (hv == 1) { s_pr[p] = rr; s_pg[p] = gg; s_pb[p] = bb; s_pT[p] = Tt; }
    __syncthreads();

    if (hv == 0) {
        rr += Tt * s_pr[p];
        gg += Tt * s_pg[p];
        bb += Tt * s_pb[p];

        const int o = (py * W + px) * 3;
        if (M > 0) {
            out[o    ] = fminf(fmaxf(rr, 1e-04f), 1.0f);
            out[o + 1] = fminf(fmaxf(gg, 1e-04f), 1.0f);
            out[o + 2] = fminf(fmaxf(bb, 1e-04f), 1.0f);
        } else {
            out[o] = 0.0f; out[o + 1] = 0.0f; out[o + 2] = 0.0f;
        }
    }
}

extern "C" void kernel_launch(void* const* d_in, const int* in_sizes, int n_in,
                              void* d_out, int out_size, void* d_ws, size_t ws_size,
                              hipStream_t stream) {
    const float* mu     = (const float*)d_in[0];
    const float* scales = (const float*)d_in[1];
    const float* quats  = (const float*)d_in[2];
    const float* cols   = (const float*)d_in[3];
    const float* opcs   = (const float*)d_in[4];
    const float* vm     = (const float*)d_in[5];
    // d_in[6] = gt (unused by forward)
    const int* focal_p  = (const int*)d_in[7];
    const int* H_p      = (const int*)d_in[8];
    const int* W_p      = (const int*)d_in[9];

    const int N = in_sizes[4];              // opcs count = number of Gaussians
    const int HW = out_size / 3;
    int W = (int)(sqrt((double)HW) + 0.5);  // 256 for this problem
    int H = HW / W;

    dim3 grid(W / TILE, H / TILE), block(512);
    fused_kernel<<<grid, block, 0, stream>>>(mu, scales, quats, cols, opcs, vm,
                                             focal_p, H_p, W_p, (float*)d_out, N);
}